// Round 1
// baseline (476.227 us; speedup 1.0000x reference)
//
#include <hip/hip_runtime.h>
#include <math.h>

#define MPTS 8192
#define DIMS 32
#define TI 16          // rows per workgroup
#define TJ 256         // cols per LDS tile
#define NTILES (MPTS/TJ)
#define SROW 36        // padded LDS stride (floats): 32 dims + norm + nu + pad, 16B-aligned
#define RT 2
#define CT 8

__device__ __forceinline__ void top4_insert(float v, float& t0, float& t1, float& t2, float& t3) {
    t3 = fminf(t3, v);
    float lo = fminf(t2, t3), hi = fmaxf(t2, t3); t2 = lo; t3 = hi;
    lo = fminf(t1, t2); hi = fmaxf(t1, t2); t1 = lo; t2 = hi;
    lo = fminf(t0, t1); hi = fmaxf(t0, t1); t0 = lo; t1 = hi;
}

// K1: row sums-of-squares for P and Q; zero the count buffers (ws is poisoned each call)
__global__ void prep_kernel(const float* __restrict__ P, const float* __restrict__ Q,
                            float* __restrict__ normP, float* __restrict__ normQ,
                            int* __restrict__ countP, int* __restrict__ countQ) {
    int t = blockIdx.x * blockDim.x + threadIdx.x;   // 0 .. 2*MPTS-1
    int r = t & (MPTS - 1);
    const float* src = (t < MPTS) ? (P + (size_t)r * DIMS) : (Q + (size_t)r * DIMS);
    float s = 0.f;
#pragma unroll
    for (int seg = 0; seg < 8; ++seg) {
        float4 v = *(const float4*)(src + seg * 4);
        s = fmaf(v.x, v.x, s); s = fmaf(v.y, v.y, s);
        s = fmaf(v.z, v.z, s); s = fmaf(v.w, v.w, s);
    }
    if (t < MPTS) { normP[r] = s; countP[r] = 0; }
    else          { normQ[r] = s; countQ[r] = 0; }
}

// K2: for each row of Y, 4th-smallest distance to all Y points (incl. self) -> nu = sqrt(max(sq,1e-12))
__global__ __launch_bounds__(256, 2)
void knn_kernel(const float* __restrict__ Y, const float* __restrict__ normY,
                float* __restrict__ nu_out) {
    __shared__ float ldsRow[TI * SROW];
    __shared__ float ldsCol[TJ * SROW];
    const int tid = threadIdx.x;
    const int row0 = blockIdx.x * TI;

    if (tid < TI * 8) {
        int r = tid >> 3, seg = tid & 7;
        *(float4*)&ldsRow[r * SROW + seg * 4] =
            *(const float4*)(Y + (size_t)(row0 + r) * DIMS + seg * 4);
        if (seg == 0) ldsRow[r * SROW + 32] = normY[row0 + r];
    }

    const int tr = tid >> 5;   // 0..7
    const int tc = tid & 31;   // 0..31
    const int r0 = tr * RT;

    float t0[RT], t1[RT], t2[RT], t3[RT];
#pragma unroll
    for (int i = 0; i < RT; ++i) t0[i] = t1[i] = t2[i] = t3[i] = 3.4e38f;

    for (int jt = 0; jt < NTILES; ++jt) {
        __syncthreads();
        {
            int gc = jt * TJ + tid;
            const float* src = Y + (size_t)gc * DIMS;
#pragma unroll
            for (int seg = 0; seg < 8; ++seg)
                *(float4*)&ldsCol[tid * SROW + seg * 4] = *(const float4*)(src + seg * 4);
            ldsCol[tid * SROW + 32] = normY[gc];
        }
        __syncthreads();

        float acc[RT][CT];
#pragma unroll
        for (int i = 0; i < RT; ++i)
#pragma unroll
            for (int j = 0; j < CT; ++j) acc[i][j] = 0.f;

#pragma unroll
        for (int kk = 0; kk < 8; ++kk) {
            float4 a[RT], b[CT];
#pragma unroll
            for (int i = 0; i < RT; ++i)
                a[i] = *(const float4*)&ldsRow[(r0 + i) * SROW + kk * 4];
#pragma unroll
            for (int j = 0; j < CT; ++j)
                b[j] = *(const float4*)&ldsCol[(tc + 32 * j) * SROW + kk * 4];
#pragma unroll
            for (int i = 0; i < RT; ++i)
#pragma unroll
                for (int j = 0; j < CT; ++j) {
                    acc[i][j] = fmaf(a[i].x, b[j].x, acc[i][j]);
                    acc[i][j] = fmaf(a[i].y, b[j].y, acc[i][j]);
                    acc[i][j] = fmaf(a[i].z, b[j].z, acc[i][j]);
                    acc[i][j] = fmaf(a[i].w, b[j].w, acc[i][j]);
                }
        }
#pragma unroll
        for (int i = 0; i < RT; ++i) {
            float ni = ldsRow[(r0 + i) * SROW + 32];
#pragma unroll
            for (int j = 0; j < CT; ++j) {
                float nj = ldsCol[(tc + 32 * j) * SROW + 32];
                float sq = ni + nj - 2.0f * acc[i][j];
                top4_insert(sq, t0[i], t1[i], t2[i], t3[i]);
            }
        }
    }

    // merge per-thread top-4 lists (32 threads per row) through LDS
    __syncthreads();
#pragma unroll
    for (int i = 0; i < RT; ++i) {
        float* dst = &ldsCol[((r0 + i) * 32 + tc) * 4];
        dst[0] = t0[i]; dst[1] = t1[i]; dst[2] = t2[i]; dst[3] = t3[i];
    }
    __syncthreads();
    if (tid < TI) {
        float a0 = 3.4e38f, a1 = a0, a2 = a0, a3 = a0;
        const float* src = &ldsCol[tid * 128];
        for (int s = 0; s < 128; ++s) top4_insert(src[s], a0, a1, a2, a3);
        nu_out[row0 + tid] = sqrtf(fmaxf(a3, 1e-12f));
    }
}

// K3: one pass over dist(P,Q); countQ[b] += (d<=nuQ[b]); countP[a] += (d<=nuP[a])
__global__ __launch_bounds__(256, 2)
void count_kernel(const float* __restrict__ P, const float* __restrict__ Q,
                  const float* __restrict__ normP, const float* __restrict__ normQ,
                  const float* __restrict__ nuP, const float* __restrict__ nuQ,
                  int* __restrict__ countP, int* __restrict__ countQ) {
    __shared__ float ldsRow[TI * SROW];
    __shared__ float ldsCol[TJ * SROW];
    __shared__ int   ldsCnt[TJ * 9];
    const int tid = threadIdx.x;
    const int row0 = blockIdx.x * TI;

    if (tid < TI * 8) {
        int r = tid >> 3, seg = tid & 7;
        *(float4*)&ldsRow[r * SROW + seg * 4] =
            *(const float4*)(P + (size_t)(row0 + r) * DIMS + seg * 4);
        if (seg == 0) {
            ldsRow[r * SROW + 32] = normP[row0 + r];
            ldsRow[r * SROW + 33] = nuP[row0 + r];
        }
    }

    const int tr = tid >> 5;
    const int tc = tid & 31;
    const int r0 = tr * RT;

    int cntP[RT];
#pragma unroll
    for (int i = 0; i < RT; ++i) cntP[i] = 0;

    for (int jt = 0; jt < NTILES; ++jt) {
        __syncthreads();
        {
            int gc = jt * TJ + tid;
            const float* src = Q + (size_t)gc * DIMS;
#pragma unroll
            for (int seg = 0; seg < 8; ++seg)
                *(float4*)&ldsCol[tid * SROW + seg * 4] = *(const float4*)(src + seg * 4);
            ldsCol[tid * SROW + 32] = normQ[gc];
            ldsCol[tid * SROW + 33] = nuQ[gc];
        }
        __syncthreads();

        float acc[RT][CT];
#pragma unroll
        for (int i = 0; i < RT; ++i)
#pragma unroll
            for (int j = 0; j < CT; ++j) acc[i][j] = 0.f;

#pragma unroll
        for (int kk = 0; kk < 8; ++kk) {
            float4 a[RT], b[CT];
#pragma unroll
            for (int i = 0; i < RT; ++i)
                a[i] = *(const float4*)&ldsRow[(r0 + i) * SROW + kk * 4];
#pragma unroll
            for (int j = 0; j < CT; ++j)
                b[j] = *(const float4*)&ldsCol[(tc + 32 * j) * SROW + kk * 4];
#pragma unroll
            for (int i = 0; i < RT; ++i)
#pragma unroll
                for (int j = 0; j < CT; ++j) {
                    acc[i][j] = fmaf(a[i].x, b[j].x, acc[i][j]);
                    acc[i][j] = fmaf(a[i].y, b[j].y, acc[i][j]);
                    acc[i][j] = fmaf(a[i].z, b[j].z, acc[i][j]);
                    acc[i][j] = fmaf(a[i].w, b[j].w, acc[i][j]);
                }
        }

        int cq[CT];
#pragma unroll
        for (int j = 0; j < CT; ++j) cq[j] = 0;

#pragma unroll
        for (int i = 0; i < RT; ++i) {
            float ni  = ldsRow[(r0 + i) * SROW + 32];
            float nuR = ldsRow[(r0 + i) * SROW + 33];
#pragma unroll
            for (int j = 0; j < CT; ++j) {
                float nj  = ldsCol[(tc + 32 * j) * SROW + 32];
                float nuC = ldsCol[(tc + 32 * j) * SROW + 33];
                float sq = ni + nj - 2.0f * acc[i][j];
                float d  = sqrtf(fmaxf(sq, 1e-12f));
                cntP[i] += (d <= nuR) ? 1 : 0;
                cq[j]   += (d <= nuC) ? 1 : 0;
            }
        }
#pragma unroll
        for (int j = 0; j < CT; ++j) ldsCnt[(tc + 32 * j) * 9 + tr] = cq[j];
        __syncthreads();
        {
            int s = 0;
#pragma unroll
            for (int u = 0; u < 8; ++u) s += ldsCnt[tid * 9 + u];
            if (s) atomicAdd(&countQ[jt * TJ + tid], s);
        }
    }

    __syncthreads();
#pragma unroll
    for (int i = 0; i < RT; ++i) ldsCnt[(r0 + i) * 32 + tc] = cntP[i];
    __syncthreads();
    if (tid < TI) {
        int s = 0;
#pragma unroll
        for (int u = 0; u < 32; ++u) s += ldsCnt[tid * 32 + u];
        countP[row0 + tid] = s;   // each row owned by exactly one workgroup
    }
}

// K4: scalar epilogue, exact fp32 clip/pow semantics of the reference
__global__ void final_kernel(const int* __restrict__ countP, const int* __restrict__ countQ,
                             const float* __restrict__ nuP, const float* __restrict__ nuQ,
                             float* __restrict__ out) {
    __shared__ int    redi[256];
    __shared__ double redd[256];
    const int tid = threadIdx.x;
    int sQ = 0, sP = 0;
    for (int j = tid; j < MPTS; j += 256) { sQ += countQ[j]; sP += countP[j]; }
    redi[tid] = sQ; __syncthreads();
    for (int o = 128; o > 0; o >>= 1) { if (tid < o) redi[tid] += redi[tid + o]; __syncthreads(); }
    int totQ = redi[0]; __syncthreads();
    redi[tid] = sP; __syncthreads();
    for (int o = 128; o > 0; o >>= 1) { if (tid < o) redi[tid] += redi[tid + o]; __syncthreads(); }
    int totP = redi[0]; __syncthreads();

    const float kq_term = 3.0f / 24576.0f;      // k_q / kq_sum (exact in fp32)
    float kpQ = (float)totQ + 1e-20f;
    float kpP = (float)totP + 1e-20f;
    double rQ = 0.0, rP = 0.0;
    for (int j = tid; j < MPTS; j += 256) {
        {
            float nu = nuQ[j];                   // rho == max(nu,1e-20) == nu (nu >= 1e-6)
            float x = nu * nu; x *= x; x *= x; x *= x; x *= x;   // nu^32, 5 squarings (XLA integer_pow)
            float inv = 1.0f / (x + 1e-20f);
            float p_den = ((float)countQ[j] / kpQ) * inv;
            p_den = fminf(fmaxf(p_den, 1e-20f), 1e10f);
            float q_den = kq_term * inv;
            q_den = fminf(fmaxf(q_den, 1e-20f), 1e10f);
            rQ += (double)((p_den / q_den) * kq_term);
        }
        {
            float nu = nuP[j];
            float x = nu * nu; x *= x; x *= x; x *= x; x *= x;
            float inv = 1.0f / (x + 1e-20f);
            float p_den = ((float)countP[j] / kpP) * inv;
            p_den = fminf(fmaxf(p_den, 1e-20f), 1e10f);
            float q_den = kq_term * inv;
            q_den = fminf(fmaxf(q_den, 1e-20f), 1e10f);
            rP += (double)((p_den / q_den) * kq_term);
        }
    }
    redd[tid] = rQ; __syncthreads();
    for (int o = 128; o > 0; o >>= 1) { if (tid < o) redd[tid] += redd[tid + o]; __syncthreads(); }
    double RQ = redd[0]; __syncthreads();
    redd[tid] = rP; __syncthreads();
    for (int o = 128; o > 0; o >>= 1) { if (tid < o) redd[tid] += redd[tid + o]; __syncthreads(); }
    if (tid == 0) {
        double RP = redd[0];
        float divP = fmaxf(0.0f, logf((float)RQ));   // alpha=2 -> 1/(alpha-1) = 1
        float divQ = fmaxf(0.0f, logf((float)RP));
        out[0] = fmaxf(divP, divQ);
    }
}

extern "C" void kernel_launch(void* const* d_in, const int* in_sizes, int n_in,
                              void* d_out, int out_size, void* d_ws, size_t ws_size,
                              hipStream_t stream) {
    const float* P = (const float*)d_in[0];
    const float* Q = (const float*)d_in[1];
    float* out = (float*)d_out;
    float* ws = (float*)d_ws;
    float* normP = ws;
    float* normQ = ws + MPTS;
    float* nuP   = ws + 2 * MPTS;
    float* nuQ   = ws + 3 * MPTS;
    int*   countP = (int*)(ws + 4 * MPTS);
    int*   countQ = (int*)(ws + 5 * MPTS);

    prep_kernel<<<(2 * MPTS) / 256, 256, 0, stream>>>(P, Q, normP, normQ, countP, countQ);
    knn_kernel<<<MPTS / TI, 256, 0, stream>>>(Q, normQ, nuQ);   // rho/nu for Y=Q (div_p)
    knn_kernel<<<MPTS / TI, 256, 0, stream>>>(P, normP, nuP);   // rho/nu for Y=P (div_q)
    count_kernel<<<MPTS / TI, 256, 0, stream>>>(P, Q, normP, normQ, nuP, nuQ, countP, countQ);
    final_kernel<<<1, 256, 0, stream>>>(countP, countQ, nuP, nuQ, out);
}

// Round 2
// 371.014 us; speedup vs baseline: 1.2836x; 1.2836x over previous
//
#include <hip/hip_runtime.h>
#include <math.h>

#define MPTS 8192
#define DIMS 32
#define TI 32          // rows per workgroup
#define TJ 256         // cols per LDS tile
#define NTILES (MPTS/TJ)
#define SROW 36        // padded LDS stride (floats): 32 dims + norm + nu + pad; 144B = 16B-aligned
#define RT 4           // rows per thread
#define CT 8           // cols per thread

__device__ __forceinline__ void top4_insert(float v, float& t0, float& t1, float& t2, float& t3) {
    t3 = fminf(t3, v);
    float lo = fminf(t2, t3), hi = fmaxf(t2, t3); t2 = lo; t3 = hi;
    lo = fminf(t1, t2); hi = fmaxf(t1, t2); t1 = lo; t2 = hi;
    lo = fminf(t0, t1); hi = fmaxf(t0, t1); t0 = lo; t1 = hi;
}

// K1: row sums-of-squares for P and Q; zero the count buffers (ws is poisoned each call)
__global__ void prep_kernel(const float* __restrict__ P, const float* __restrict__ Q,
                            float* __restrict__ normP, float* __restrict__ normQ,
                            int* __restrict__ countP, int* __restrict__ countQ) {
    int t = blockIdx.x * blockDim.x + threadIdx.x;   // 0 .. 2*MPTS-1
    int r = t & (MPTS - 1);
    const float* src = (t < MPTS) ? (P + (size_t)r * DIMS) : (Q + (size_t)r * DIMS);
    float s = 0.f;
#pragma unroll
    for (int seg = 0; seg < 8; ++seg) {
        float4 v = *(const float4*)(src + seg * 4);
        s = fmaf(v.x, v.x, s); s = fmaf(v.y, v.y, s);
        s = fmaf(v.z, v.z, s); s = fmaf(v.w, v.w, s);
    }
    if (t < MPTS) { normP[r] = s; countP[r] = 0; }
    else          { normQ[r] = s; countQ[r] = 0; }
}

// K2: fused knn for both matrices. blockIdx.y==0 -> Y=Q (nuQ), ==1 -> Y=P (nuP).
// Each wg: 32 rows vs all 8192 cols; RT=4 rows/thread (broadcast LDS reads), CT=8 cols/thread.
__global__ __launch_bounds__(256, 2)
void knn_kernel(const float* __restrict__ P, const float* __restrict__ Q,
                const float* __restrict__ normP, const float* __restrict__ normQ,
                float* __restrict__ nuP, float* __restrict__ nuQ) {
    __shared__ float ldsCol[TJ * SROW];   // also reused as merge scratch (needs 4096 floats)
    __shared__ float ldsRow[TI * SROW];
    __shared__ float ldsM[TI * 8 * 4];
    const float* Y;  const float* normY;  float* nu_out;
    if (blockIdx.y == 0) { Y = Q; normY = normQ; nu_out = nuQ; }
    else                 { Y = P; normY = normP; nu_out = nuP; }
    const int tid = threadIdx.x;
    const int row0 = blockIdx.x * TI;

    {   // stage 32 rows (8 segs each) — exactly 256 threads
        int r = tid >> 3, seg = tid & 7;
        *(float4*)&ldsRow[r * SROW + seg * 4] =
            *(const float4*)(Y + (size_t)(row0 + r) * DIMS + seg * 4);
        if (seg == 0) ldsRow[r * SROW + 32] = normY[row0 + r];
    }

    const int tr = tid >> 5;          // 0..7
    const int tc = tid & 31;          // 0..31
    const int r0 = tr * RT;
    const float* baseA = &ldsRow[r0 * SROW];
    const float* baseB = &ldsCol[tc * SROW];

    float t0[RT], t1[RT], t2[RT], t3[RT];
#pragma unroll
    for (int i = 0; i < RT; ++i) t0[i] = t1[i] = t2[i] = t3[i] = 3.4e38f;

    for (int jt = 0; jt < NTILES; ++jt) {
        __syncthreads();
        {
            int gc = jt * TJ + tid;
            const float* src = Y + (size_t)gc * DIMS;
#pragma unroll
            for (int seg = 0; seg < 8; ++seg)
                *(float4*)&ldsCol[tid * SROW + seg * 4] = *(const float4*)(src + seg * 4);
            ldsCol[tid * SROW + 32] = normY[gc];
        }
        __syncthreads();

        float acc[RT][CT];
#pragma unroll
        for (int i = 0; i < RT; ++i)
#pragma unroll
            for (int j = 0; j < CT; ++j) acc[i][j] = 0.f;

#pragma unroll
        for (int kk = 0; kk < 8; ++kk) {
            float4 a[RT], b[CT];
#pragma unroll
            for (int i = 0; i < RT; ++i)
                a[i] = *(const float4*)&baseA[i * SROW + kk * 4];       // broadcast within tc-group
#pragma unroll
            for (int j = 0; j < CT; ++j)
                b[j] = *(const float4*)&baseB[32 * j * SROW + kk * 4];  // imm-offset ds_read_b128
#pragma unroll
            for (int i = 0; i < RT; ++i)
#pragma unroll
                for (int j = 0; j < CT; ++j) {
                    acc[i][j] = fmaf(a[i].x, b[j].x, acc[i][j]);
                    acc[i][j] = fmaf(a[i].y, b[j].y, acc[i][j]);
                    acc[i][j] = fmaf(a[i].z, b[j].z, acc[i][j]);
                    acc[i][j] = fmaf(a[i].w, b[j].w, acc[i][j]);
                }
        }
#pragma unroll
        for (int i = 0; i < RT; ++i) {
            float ni = baseA[i * SROW + 32];
#pragma unroll
            for (int j = 0; j < CT; ++j) {
                float nj = baseB[32 * j * SROW + 32];
                float sq = ni + nj - 2.0f * acc[i][j];
                top4_insert(sq, t0[i], t1[i], t2[i], t3[i]);
            }
        }
    }

    // merge per-thread top-4 lists (32 tc-threads per row) — two-stage through LDS
    __syncthreads();
#pragma unroll
    for (int i = 0; i < RT; ++i)
        *(float4*)&ldsCol[((r0 + i) * 32 + tc) * 4] = make_float4(t0[i], t1[i], t2[i], t3[i]);
    __syncthreads();
    {
        int row = tid & 31, seg = tid >> 5;
        float a0 = 3.4e38f, a1 = a0, a2 = a0, a3 = a0;
        const float* src = &ldsCol[row * 128 + seg * 16];
#pragma unroll
        for (int s = 0; s < 16; ++s) top4_insert(src[s], a0, a1, a2, a3);
        *(float4*)&ldsM[(row * 8 + seg) * 4] = make_float4(a0, a1, a2, a3);
    }
    __syncthreads();
    if (tid < TI) {
        float a0 = 3.4e38f, a1 = a0, a2 = a0, a3 = a0;
        const float* src = &ldsM[tid * 32];
#pragma unroll
        for (int s = 0; s < 32; ++s) top4_insert(src[s], a0, a1, a2, a3);
        nu_out[row0 + tid] = sqrtf(fmaxf(a3, 1e-12f));
    }
}

// K3: one pass over dist(P,Q), split over column halves (blockIdx.y).
// countQ[b] += (d<=nuQ[b]); countP[a] += (d<=nuP[a]); both via atomics (rare).
__global__ __launch_bounds__(256, 2)
void count_kernel(const float* __restrict__ P, const float* __restrict__ Q,
                  const float* __restrict__ normP, const float* __restrict__ normQ,
                  const float* __restrict__ nuP, const float* __restrict__ nuQ,
                  int* __restrict__ countP, int* __restrict__ countQ) {
    __shared__ float ldsRow[TI * SROW];
    __shared__ float ldsCol[TJ * SROW];
    __shared__ int   ldsCnt[TJ * 9];      // also reused for the 32x33 row reduction (1056 ints)
    const int tid = threadIdx.x;
    const int row0 = blockIdx.x * TI;

    {
        int r = tid >> 3, seg = tid & 7;
        *(float4*)&ldsRow[r * SROW + seg * 4] =
            *(const float4*)(P + (size_t)(row0 + r) * DIMS + seg * 4);
        if (seg == 0) {
            ldsRow[r * SROW + 32] = normP[row0 + r];
            ldsRow[r * SROW + 33] = nuP[row0 + r];
        }
    }

    const int tr = tid >> 5;
    const int tc = tid & 31;
    const int r0 = tr * RT;
    const float* baseA = &ldsRow[r0 * SROW];
    const float* baseB = &ldsCol[tc * SROW];

    int cntP[RT];
#pragma unroll
    for (int i = 0; i < RT; ++i) cntP[i] = 0;

    const int jt0 = blockIdx.y * (NTILES / 2);
    const int jt1 = jt0 + (NTILES / 2);
    for (int jt = jt0; jt < jt1; ++jt) {
        __syncthreads();
        {
            int gc = jt * TJ + tid;
            const float* src = Q + (size_t)gc * DIMS;
#pragma unroll
            for (int seg = 0; seg < 8; ++seg)
                *(float4*)&ldsCol[tid * SROW + seg * 4] = *(const float4*)(src + seg * 4);
            ldsCol[tid * SROW + 32] = normQ[gc];
            ldsCol[tid * SROW + 33] = nuQ[gc];
        }
        __syncthreads();

        float acc[RT][CT];
#pragma unroll
        for (int i = 0; i < RT; ++i)
#pragma unroll
            for (int j = 0; j < CT; ++j) acc[i][j] = 0.f;

#pragma unroll
        for (int kk = 0; kk < 8; ++kk) {
            float4 a[RT], b[CT];
#pragma unroll
            for (int i = 0; i < RT; ++i)
                a[i] = *(const float4*)&baseA[i * SROW + kk * 4];
#pragma unroll
            for (int j = 0; j < CT; ++j)
                b[j] = *(const float4*)&baseB[32 * j * SROW + kk * 4];
#pragma unroll
            for (int i = 0; i < RT; ++i)
#pragma unroll
                for (int j = 0; j < CT; ++j) {
                    acc[i][j] = fmaf(a[i].x, b[j].x, acc[i][j]);
                    acc[i][j] = fmaf(a[i].y, b[j].y, acc[i][j]);
                    acc[i][j] = fmaf(a[i].z, b[j].z, acc[i][j]);
                    acc[i][j] = fmaf(a[i].w, b[j].w, acc[i][j]);
                }
        }

        int cq[CT];
#pragma unroll
        for (int j = 0; j < CT; ++j) cq[j] = 0;
#pragma unroll
        for (int i = 0; i < RT; ++i) {
            float ni  = baseA[i * SROW + 32];
            float nuR = baseA[i * SROW + 33];
#pragma unroll
            for (int j = 0; j < CT; ++j) {
                float nj  = baseB[32 * j * SROW + 32];
                float nuC = baseB[32 * j * SROW + 33];
                float sq = ni + nj - 2.0f * acc[i][j];
                float d  = sqrtf(fmaxf(sq, 1e-12f));     // exact reference semantics
                cntP[i] += (d <= nuR) ? 1 : 0;
                cq[j]   += (d <= nuC) ? 1 : 0;
            }
        }
#pragma unroll
        for (int j = 0; j < CT; ++j) ldsCnt[(tc + 32 * j) * 9 + tr] = cq[j];
        __syncthreads();
        {
            int s = 0;
#pragma unroll
            for (int u = 0; u < 8; ++u) s += ldsCnt[tid * 9 + u];
            if (s) atomicAdd(&countQ[jt * TJ + tid], s);
        }
    }

    __syncthreads();
#pragma unroll
    for (int i = 0; i < RT; ++i) ldsCnt[(r0 + i) * 33 + tc] = cntP[i];
    __syncthreads();
    if (tid < TI) {
        int s = 0;
#pragma unroll
        for (int u = 0; u < 32; ++u) s += ldsCnt[tid * 33 + u];
        if (s) atomicAdd(&countP[row0 + tid], s);
    }
}

// K4: scalar epilogue, exact fp32 clip/pow semantics of the reference
__global__ void final_kernel(const int* __restrict__ countP, const int* __restrict__ countQ,
                             const float* __restrict__ nuP, const float* __restrict__ nuQ,
                             float* __restrict__ out) {
    __shared__ int    redi[256];
    __shared__ double redd[256];
    const int tid = threadIdx.x;
    int sQ = 0, sP = 0;
    for (int j = tid; j < MPTS; j += 256) { sQ += countQ[j]; sP += countP[j]; }
    redi[tid] = sQ; __syncthreads();
    for (int o = 128; o > 0; o >>= 1) { if (tid < o) redi[tid] += redi[tid + o]; __syncthreads(); }
    int totQ = redi[0]; __syncthreads();
    redi[tid] = sP; __syncthreads();
    for (int o = 128; o > 0; o >>= 1) { if (tid < o) redi[tid] += redi[tid + o]; __syncthreads(); }
    int totP = redi[0]; __syncthreads();

    const float kq_term = 3.0f / 24576.0f;      // k_q / kq_sum (exact in fp32)
    float kpQ = (float)totQ + 1e-20f;
    float kpP = (float)totP + 1e-20f;
    double rQ = 0.0, rP = 0.0;
    for (int j = tid; j < MPTS; j += 256) {
        {
            float nu = nuQ[j];                   // rho == max(nu,1e-20) == nu (nu >= 1e-6)
            float x = nu * nu; x *= x; x *= x; x *= x; x *= x;   // nu^32, 5 squarings (XLA integer_pow)
            float inv = 1.0f / (x + 1e-20f);
            float p_den = ((float)countQ[j] / kpQ) * inv;
            p_den = fminf(fmaxf(p_den, 1e-20f), 1e10f);
            float q_den = kq_term * inv;
            q_den = fminf(fmaxf(q_den, 1e-20f), 1e10f);
            rQ += (double)((p_den / q_den) * kq_term);
        }
        {
            float nu = nuP[j];
            float x = nu * nu; x *= x; x *= x; x *= x; x *= x;
            float inv = 1.0f / (x + 1e-20f);
            float p_den = ((float)countP[j] / kpP) * inv;
            p_den = fminf(fmaxf(p_den, 1e-20f), 1e10f);
            float q_den = kq_term * inv;
            q_den = fminf(fmaxf(q_den, 1e-20f), 1e10f);
            rP += (double)((p_den / q_den) * kq_term);
        }
    }
    redd[tid] = rQ; __syncthreads();
    for (int o = 128; o > 0; o >>= 1) { if (tid < o) redd[tid] += redd[tid + o]; __syncthreads(); }
    double RQ = redd[0]; __syncthreads();
    redd[tid] = rP; __syncthreads();
    for (int o = 128; o > 0; o >>= 1) { if (tid < o) redd[tid] += redd[tid + o]; __syncthreads(); }
    if (tid == 0) {
        double RP = redd[0];
        float divP = fmaxf(0.0f, logf((float)RQ));   // alpha=2 -> 1/(alpha-1) = 1
        float divQ = fmaxf(0.0f, logf((float)RP));
        out[0] = fmaxf(divP, divQ);
    }
}

extern "C" void kernel_launch(void* const* d_in, const int* in_sizes, int n_in,
                              void* d_out, int out_size, void* d_ws, size_t ws_size,
                              hipStream_t stream) {
    const float* P = (const float*)d_in[0];
    const float* Q = (const float*)d_in[1];
    float* out = (float*)d_out;
    float* ws = (float*)d_ws;
    float* normP = ws;
    float* normQ = ws + MPTS;
    float* nuP   = ws + 2 * MPTS;
    float* nuQ   = ws + 3 * MPTS;
    int*   countP = (int*)(ws + 4 * MPTS);
    int*   countQ = (int*)(ws + 5 * MPTS);

    prep_kernel<<<(2 * MPTS) / 256, 256, 0, stream>>>(P, Q, normP, normQ, countP, countQ);
    knn_kernel<<<dim3(MPTS / TI, 2), 256, 0, stream>>>(P, Q, normP, normQ, nuP, nuQ);
    count_kernel<<<dim3(MPTS / TI, 2), 256, 0, stream>>>(P, Q, normP, normQ, nuP, nuQ, countP, countQ);
    final_kernel<<<1, 256, 0, stream>>>(countP, countQ, nuP, nuQ, out);
}

// Round 3
// 176.888 us; speedup vs baseline: 2.6923x; 2.0975x over previous
//
#include <hip/hip_runtime.h>
#include <math.h>

#define MPTS 8192
#define DIMS 32

typedef __bf16 bf16x8 __attribute__((ext_vector_type(8)));
typedef float  f32x4  __attribute__((ext_vector_type(4)));

__device__ __forceinline__ void top4_insert(float v, float& t0, float& t1, float& t2, float& t3) {
    t3 = fminf(t3, v);
    float lo = fminf(t2, t3), hi = fmaxf(t2, t3); t2 = lo; t3 = hi;
    lo = fminf(t1, t2); hi = fmaxf(t1, t2); t1 = lo; t2 = hi;
    lo = fminf(t0, t1); hi = fmaxf(t0, t1); t0 = lo; t1 = hi;
}

__device__ __forceinline__ unsigned short f32_to_bf16_rne(float x) {
    unsigned u = __float_as_uint(x);
    unsigned r = u + 0x7FFFu + ((u >> 16) & 1u);
    return (unsigned short)(r >> 16);
}
__device__ __forceinline__ float bf16us_to_f32(unsigned short h) {
    return __uint_as_float(((unsigned)h) << 16);
}

// K1: norms + hi/lo bf16 split of P and Q (row-major, so MFMA A/B frags are
// contiguous 16B per lane: row = lane&15, k-octet = lane>>4).
// 65536 threads: thread -> (matrix, row, 8-elem segment).
__global__ void prep_kernel(const float* __restrict__ P, const float* __restrict__ Q,
                            unsigned short* __restrict__ Phi, unsigned short* __restrict__ Plo,
                            unsigned short* __restrict__ Qhi, unsigned short* __restrict__ Qlo,
                            float* __restrict__ normP, float* __restrict__ normQ) {
    int t = blockIdx.x * 256 + threadIdx.x;          // 0 .. 65535
    int mat = t >> 15;                               // 0 = P, 1 = Q
    int idx = t & 32767;
    int r = idx >> 2, seg = idx & 3;                 // 8 elements per thread
    const float* X = mat ? Q : P;
    unsigned short* Xhi = mat ? Qhi : Phi;
    unsigned short* Xlo = mat ? Qlo : Plo;
    float* nX = mat ? normQ : normP;

    const float* src = X + (size_t)r * DIMS + seg * 8;
    float4 v0 = *(const float4*)(src);
    float4 v1 = *(const float4*)(src + 4);
    float f[8] = {v0.x, v0.y, v0.z, v0.w, v1.x, v1.y, v1.z, v1.w};

    float p = 0.f;
#pragma unroll
    for (int k = 0; k < 8; ++k) p = fmaf(f[k], f[k], p);
    p += __shfl_xor(p, 1);
    p += __shfl_xor(p, 2);      // seg groups of 4 are lane-aligned (4 | 64)
    if (seg == 0) nX[r] = p;

    unsigned short h[8], lo[8];
#pragma unroll
    for (int k = 0; k < 8; ++k) {
        h[k] = f32_to_bf16_rne(f[k]);
        float res = f[k] - bf16us_to_f32(h[k]);      // exact (Sterbenz-range)
        lo[k] = f32_to_bf16_rne(res);
    }
    uint4 ph, pl;
    ph.x = (unsigned)h[0] | ((unsigned)h[1] << 16);
    ph.y = (unsigned)h[2] | ((unsigned)h[3] << 16);
    ph.z = (unsigned)h[4] | ((unsigned)h[5] << 16);
    ph.w = (unsigned)h[6] | ((unsigned)h[7] << 16);
    pl.x = (unsigned)lo[0] | ((unsigned)lo[1] << 16);
    pl.y = (unsigned)lo[2] | ((unsigned)lo[3] << 16);
    pl.z = (unsigned)lo[4] | ((unsigned)lo[5] << 16);
    pl.w = (unsigned)lo[6] | ((unsigned)lo[7] << 16);
    *(uint4*)(Xhi + (size_t)r * DIMS + seg * 8) = ph;
    *(uint4*)(Xlo + (size_t)r * DIMS + seg * 8) = pl;
}

// K2: kNN via bf16x2-split MFMA. blockIdx.y: 0 -> Y=Q (nusqQ), 1 -> Y=P (nusqP).
// Block = 512 thr = 8 waves; block owns 32 queries; wave w handles candidate
// tiles [w*64, w*64+64) of 16 rows each. dot = (ahi+alo)x(bhi+blo), 4 MFMAs, K=32.
// C layout: col = lane&15 (query), row = (lane>>4)*4+reg (candidate).
__global__ __launch_bounds__(512, 4)
void knn_mfma(const unsigned short* __restrict__ Phi, const unsigned short* __restrict__ Plo,
              const unsigned short* __restrict__ Qhi, const unsigned short* __restrict__ Qlo,
              const float* __restrict__ normP, const float* __restrict__ normQ,
              float* __restrict__ nusqP, float* __restrict__ nusqQ) {
    __shared__ float ldsM[32 * 32 * 4];    // [query][list 0..31][4]
    __shared__ float ldsM2[32 * 8 * 4];    // [query][chunk 0..7][4]
    const unsigned short *Yhi, *Ylo; const float* nY; float* out;
    if (blockIdx.y == 0) { Yhi = Qhi; Ylo = Qlo; nY = normQ; out = nusqQ; }
    else                 { Yhi = Phi; Ylo = Plo; nY = normP; out = nusqP; }
    const int tid = threadIdx.x;
    const int w = tid >> 6, l = tid & 63, q = l & 15, quad = l >> 4;
    const int q0 = blockIdx.x * 32;

    const int rb0 = q0 + q, rb1 = q0 + 16 + q;
    bf16x8 bh0 = *(const bf16x8*)(Yhi + rb0 * DIMS + quad * 8);
    bf16x8 bl0 = *(const bf16x8*)(Ylo + rb0 * DIMS + quad * 8);
    bf16x8 bh1 = *(const bf16x8*)(Yhi + rb1 * DIMS + quad * 8);
    bf16x8 bl1 = *(const bf16x8*)(Ylo + rb1 * DIMS + quad * 8);
    const float nB0 = nY[rb0], nB1 = nY[rb1];

    float t0[2], t1[2], t2[2], t3[2];
#pragma unroll
    for (int s = 0; s < 2; ++s) t0[s] = t1[s] = t2[s] = t3[s] = 3.4e38f;

    for (int i = 0; i < 64; ++i) {
        const int cbase = (w * 64 + i) * 16;
        const int ao = (cbase + q) * DIMS + quad * 8;
        bf16x8 ah = *(const bf16x8*)(Yhi + ao);
        bf16x8 al = *(const bf16x8*)(Ylo + ao);
        f32x4 acc0 = {0.f, 0.f, 0.f, 0.f}, acc1 = {0.f, 0.f, 0.f, 0.f};
        acc0 = __builtin_amdgcn_mfma_f32_16x16x32_bf16(al, bl0, acc0, 0, 0, 0);
        acc0 = __builtin_amdgcn_mfma_f32_16x16x32_bf16(al, bh0, acc0, 0, 0, 0);
        acc0 = __builtin_amdgcn_mfma_f32_16x16x32_bf16(ah, bl0, acc0, 0, 0, 0);
        acc0 = __builtin_amdgcn_mfma_f32_16x16x32_bf16(ah, bh0, acc0, 0, 0, 0);
        acc1 = __builtin_amdgcn_mfma_f32_16x16x32_bf16(al, bl1, acc1, 0, 0, 0);
        acc1 = __builtin_amdgcn_mfma_f32_16x16x32_bf16(al, bh1, acc1, 0, 0, 0);
        acc1 = __builtin_amdgcn_mfma_f32_16x16x32_bf16(ah, bl1, acc1, 0, 0, 0);
        acc1 = __builtin_amdgcn_mfma_f32_16x16x32_bf16(ah, bh1, acc1, 0, 0, 0);
        float4 nA = *(const float4*)(nY + cbase + quad * 4);
        float na[4] = {nA.x, nA.y, nA.z, nA.w};
#pragma unroll
        for (int r = 0; r < 4; ++r) {
            float s0 = fmaf(-2.f, acc0[r], na[r] + nB0);
            top4_insert(s0, t0[0], t1[0], t2[0], t3[0]);
            float s1 = fmaf(-2.f, acc1[r], na[r] + nB1);
            top4_insert(s1, t0[1], t1[1], t2[1], t3[1]);
        }
    }

#pragma unroll
    for (int s = 0; s < 2; ++s) {
        int li = ((q + s * 16) * 32 + (w * 4 + quad)) * 4;
        *(float4*)&ldsM[li] = make_float4(t0[s], t1[s], t2[s], t3[s]);
    }
    __syncthreads();
    if (tid < 256) {
        int qq = tid >> 3, c = tid & 7;
        float a0 = 3.4e38f, a1 = a0, a2 = a0, a3 = a0;
        const float* src = &ldsM[(qq * 32 + c * 4) * 4];
#pragma unroll
        for (int s = 0; s < 16; ++s) top4_insert(src[s], a0, a1, a2, a3);
        *(float4*)&ldsM2[(qq * 8 + c) * 4] = make_float4(a0, a1, a2, a3);
    }
    __syncthreads();
    if (tid < 32) {
        float a0 = 3.4e38f, a1 = a0, a2 = a0, a3 = a0;
        const float* src = &ldsM2[tid * 32];
#pragma unroll
        for (int s = 0; s < 32; ++s) top4_insert(src[s], a0, a1, a2, a3);
        out[q0 + tid] = fmaxf(a3, 1e-12f);    // nu^2 (sq domain)
    }
}

// K3: counts via the same structure. blockIdx.y==0: queries=Q (thresh nusqQ,
// out countQ), cands=P. ==1: queries=P, cands=Q, out countP.
// Compare in sq domain: d<=rho  <=>  sq<=nusq (monotone sqrt).
__global__ __launch_bounds__(512, 4)
void count_mfma(const unsigned short* __restrict__ Phi, const unsigned short* __restrict__ Plo,
                const unsigned short* __restrict__ Qhi, const unsigned short* __restrict__ Qlo,
                const float* __restrict__ normP, const float* __restrict__ normQ,
                const float* __restrict__ nusqP, const float* __restrict__ nusqQ,
                int* __restrict__ countP, int* __restrict__ countQ) {
    __shared__ int ldsC[32 * 32];          // [query][list]
    const unsigned short *Ahi, *Alo, *Bhi, *Blo;
    const float *nCand, *nQry, *thB; int* out;
    if (blockIdx.y == 0) { Ahi = Phi; Alo = Plo; Bhi = Qhi; Blo = Qlo;
                           nCand = normP; nQry = normQ; thB = nusqQ; out = countQ; }
    else                 { Ahi = Qhi; Alo = Qlo; Bhi = Phi; Blo = Plo;
                           nCand = normQ; nQry = normP; thB = nusqP; out = countP; }
    const int tid = threadIdx.x;
    const int w = tid >> 6, l = tid & 63, q = l & 15, quad = l >> 4;
    const int q0 = blockIdx.x * 32;

    const int rb0 = q0 + q, rb1 = q0 + 16 + q;
    bf16x8 bh0 = *(const bf16x8*)(Bhi + rb0 * DIMS + quad * 8);
    bf16x8 bl0 = *(const bf16x8*)(Blo + rb0 * DIMS + quad * 8);
    bf16x8 bh1 = *(const bf16x8*)(Bhi + rb1 * DIMS + quad * 8);
    bf16x8 bl1 = *(const bf16x8*)(Blo + rb1 * DIMS + quad * 8);
    const float nB0 = nQry[rb0], nB1 = nQry[rb1];
    const float th0 = thB[rb0],  th1 = thB[rb1];

    int cnt0 = 0, cnt1 = 0;
    for (int i = 0; i < 64; ++i) {
        const int cbase = (w * 64 + i) * 16;
        const int ao = (cbase + q) * DIMS + quad * 8;
        bf16x8 ah = *(const bf16x8*)(Ahi + ao);
        bf16x8 al = *(const bf16x8*)(Alo + ao);
        f32x4 acc0 = {0.f, 0.f, 0.f, 0.f}, acc1 = {0.f, 0.f, 0.f, 0.f};
        acc0 = __builtin_amdgcn_mfma_f32_16x16x32_bf16(al, bl0, acc0, 0, 0, 0);
        acc0 = __builtin_amdgcn_mfma_f32_16x16x32_bf16(al, bh0, acc0, 0, 0, 0);
        acc0 = __builtin_amdgcn_mfma_f32_16x16x32_bf16(ah, bl0, acc0, 0, 0, 0);
        acc0 = __builtin_amdgcn_mfma_f32_16x16x32_bf16(ah, bh0, acc0, 0, 0, 0);
        acc1 = __builtin_amdgcn_mfma_f32_16x16x32_bf16(al, bl1, acc1, 0, 0, 0);
        acc1 = __builtin_amdgcn_mfma_f32_16x16x32_bf16(al, bh1, acc1, 0, 0, 0);
        acc1 = __builtin_amdgcn_mfma_f32_16x16x32_bf16(ah, bl1, acc1, 0, 0, 0);
        acc1 = __builtin_amdgcn_mfma_f32_16x16x32_bf16(ah, bh1, acc1, 0, 0, 0);
        float4 nA = *(const float4*)(nCand + cbase + quad * 4);
        float na[4] = {nA.x, nA.y, nA.z, nA.w};
#pragma unroll
        for (int r = 0; r < 4; ++r) {
            float s0 = fmaf(-2.f, acc0[r], na[r] + nB0);
            cnt0 += (s0 <= th0) ? 1 : 0;
            float s1 = fmaf(-2.f, acc1[r], na[r] + nB1);
            cnt1 += (s1 <= th1) ? 1 : 0;
        }
    }
    ldsC[q * 32 + (w * 4 + quad)] = cnt0;
    ldsC[(q + 16) * 32 + (w * 4 + quad)] = cnt1;
    __syncthreads();
    if (tid < 32) {
        int s = 0;
#pragma unroll
        for (int u = 0; u < 32; ++u) s += ldsC[tid * 32 + u];
        out[q0 + tid] = s;     // each query owned by exactly one block
    }
}

// K4: scalar epilogue, exact fp32 clip/pow semantics of the reference
__global__ void final_kernel(const int* __restrict__ countP, const int* __restrict__ countQ,
                             const float* __restrict__ nusqP, const float* __restrict__ nusqQ,
                             float* __restrict__ out) {
    __shared__ int    redi[256];
    __shared__ double redd[256];
    const int tid = threadIdx.x;
    int sQ = 0, sP = 0;
    for (int j = tid; j < MPTS; j += 256) { sQ += countQ[j]; sP += countP[j]; }
    redi[tid] = sQ; __syncthreads();
    for (int o = 128; o > 0; o >>= 1) { if (tid < o) redi[tid] += redi[tid + o]; __syncthreads(); }
    int totQ = redi[0]; __syncthreads();
    redi[tid] = sP; __syncthreads();
    for (int o = 128; o > 0; o >>= 1) { if (tid < o) redi[tid] += redi[tid + o]; __syncthreads(); }
    int totP = redi[0]; __syncthreads();

    const float kq_term = 3.0f / 24576.0f;      // k_q / kq_sum (exact in fp32)
    float kpQ = (float)totQ + 1e-20f;
    float kpP = (float)totP + 1e-20f;
    double rQ = 0.0, rP = 0.0;
    for (int j = tid; j < MPTS; j += 256) {
        {
            float nu = sqrtf(nusqQ[j]);          // = sqrt(max(knn_sq,1e-12)), as reference
            float x = nu * nu; x *= x; x *= x; x *= x; x *= x;   // nu^32 via 5 squarings
            float inv = 1.0f / (x + 1e-20f);
            float p_den = ((float)countQ[j] / kpQ) * inv;
            p_den = fminf(fmaxf(p_den, 1e-20f), 1e10f);
            float q_den = kq_term * inv;
            q_den = fminf(fmaxf(q_den, 1e-20f), 1e10f);
            rQ += (double)((p_den / q_den) * kq_term);
        }
        {
            float nu = sqrtf(nusqP[j]);
            float x = nu * nu; x *= x; x *= x; x *= x; x *= x;
            float inv = 1.0f / (x + 1e-20f);
            float p_den = ((float)countP[j] / kpP) * inv;
            p_den = fminf(fmaxf(p_den, 1e-20f), 1e10f);
            float q_den = kq_term * inv;
            q_den = fminf(fmaxf(q_den, 1e-20f), 1e10f);
            rP += (double)((p_den / q_den) * kq_term);
        }
    }
    redd[tid] = rQ; __syncthreads();
    for (int o = 128; o > 0; o >>= 1) { if (tid < o) redd[tid] += redd[tid + o]; __syncthreads(); }
    double RQ = redd[0]; __syncthreads();
    redd[tid] = rP; __syncthreads();
    for (int o = 128; o > 0; o >>= 1) { if (tid < o) redd[tid] += redd[tid + o]; __syncthreads(); }
    if (tid == 0) {
        double RP = redd[0];
        float divP = fmaxf(0.0f, logf((float)RQ));   // alpha=2 -> 1/(alpha-1) = 1
        float divQ = fmaxf(0.0f, logf((float)RP));
        out[0] = fmaxf(divP, divQ);
    }
}

extern "C" void kernel_launch(void* const* d_in, const int* in_sizes, int n_in,
                              void* d_out, int out_size, void* d_ws, size_t ws_size,
                              hipStream_t stream) {
    const float* P = (const float*)d_in[0];
    const float* Q = (const float*)d_in[1];
    float* out = (float*)d_out;

    // ws layout: Phi,Plo,Qhi,Qlo (512 KB each) + norms/nusq/counts (32 KB each) = ~2.25 MB
    unsigned short* Phi = (unsigned short*)d_ws;
    unsigned short* Plo = Phi + MPTS * DIMS;
    unsigned short* Qhi = Plo + MPTS * DIMS;
    unsigned short* Qlo = Qhi + MPTS * DIMS;
    float* normP = (float*)(Qlo + MPTS * DIMS);
    float* normQ = normP + MPTS;
    float* nusqP = normQ + MPTS;
    float* nusqQ = nusqP + MPTS;
    int* countP  = (int*)(nusqQ + MPTS);
    int* countQ  = countP + MPTS;

    prep_kernel<<<256, 256, 0, stream>>>(P, Q, Phi, Plo, Qhi, Qlo, normP, normQ);
    knn_mfma<<<dim3(MPTS / 32, 2), 512, 0, stream>>>(Phi, Plo, Qhi, Qlo, normP, normQ, nusqP, nusqQ);
    count_mfma<<<dim3(MPTS / 32, 2), 512, 0, stream>>>(Phi, Plo, Qhi, Qlo, normP, normQ,
                                                       nusqP, nusqQ, countP, countQ);
    final_kernel<<<1, 256, 0, stream>>>(countP, countQ, nusqP, nusqQ, out);
}

// Round 4
// 161.940 us; speedup vs baseline: 2.9408x; 1.0923x over previous
//
#include <hip/hip_runtime.h>
#include <math.h>

#define MPTS 8192
#define DIMS 32

typedef __bf16 bf16x8 __attribute__((ext_vector_type(8)));
typedef float  f32x4  __attribute__((ext_vector_type(4)));

// Insert v into sorted-DESCENDING top-4 (t0>=t1>=t2>=t3): 1 max + 3 med3.
__device__ __forceinline__ void top4L_insert(float v, float& t0, float& t1, float& t2, float& t3) {
    float n0 = fmaxf(t0, v);
    float n1 = __builtin_amdgcn_fmed3f(v, t0, t1);
    float n2 = __builtin_amdgcn_fmed3f(v, t1, t2);
    float n3 = __builtin_amdgcn_fmed3f(v, t2, t3);
    t0 = n0; t1 = n1; t2 = n2; t3 = n3;
}

__device__ __forceinline__ unsigned short f32_to_bf16_rne(float x) {
    unsigned u = __float_as_uint(x);
    unsigned r = u + 0x7FFFu + ((u >> 16) & 1u);
    return (unsigned short)(r >> 16);
}
__device__ __forceinline__ float bf16us_to_f32(unsigned short h) {
    return __uint_as_float(((unsigned)h) << 16);
}

// K1: hi/lo bf16 split of P,Q + norms pre-scaled by -0.5 (so MFMA acc-init
// yields acc = dot - (na+nb)/2 = -sq/2 directly).
__global__ void prep_kernel(const float* __restrict__ P, const float* __restrict__ Q,
                            unsigned short* __restrict__ Phi, unsigned short* __restrict__ Plo,
                            unsigned short* __restrict__ Qhi, unsigned short* __restrict__ Qlo,
                            float* __restrict__ normP, float* __restrict__ normQ) {
    int t = blockIdx.x * 256 + threadIdx.x;          // 0 .. 65535
    int mat = t >> 15;                               // 0 = P, 1 = Q
    int idx = t & 32767;
    int r = idx >> 2, seg = idx & 3;                 // 8 elements per thread
    const float* X = mat ? Q : P;
    unsigned short* Xhi = mat ? Qhi : Phi;
    unsigned short* Xlo = mat ? Qlo : Plo;
    float* nX = mat ? normQ : normP;

    const float* src = X + (size_t)r * DIMS + seg * 8;
    float4 v0 = *(const float4*)(src);
    float4 v1 = *(const float4*)(src + 4);
    float f[8] = {v0.x, v0.y, v0.z, v0.w, v1.x, v1.y, v1.z, v1.w};

    float p = 0.f;
#pragma unroll
    for (int k = 0; k < 8; ++k) p = fmaf(f[k], f[k], p);
    p += __shfl_xor(p, 1);
    p += __shfl_xor(p, 2);      // seg groups of 4 are lane-aligned
    if (seg == 0) nX[r] = -0.5f * p;                 // pre-scaled norm

    unsigned short h[8], lo[8];
#pragma unroll
    for (int k = 0; k < 8; ++k) {
        h[k] = f32_to_bf16_rne(f[k]);
        float res = f[k] - bf16us_to_f32(h[k]);      // exact residual
        lo[k] = f32_to_bf16_rne(res);
    }
    uint4 ph, pl;
    ph.x = (unsigned)h[0] | ((unsigned)h[1] << 16);
    ph.y = (unsigned)h[2] | ((unsigned)h[3] << 16);
    ph.z = (unsigned)h[4] | ((unsigned)h[5] << 16);
    ph.w = (unsigned)h[6] | ((unsigned)h[7] << 16);
    pl.x = (unsigned)lo[0] | ((unsigned)lo[1] << 16);
    pl.y = (unsigned)lo[2] | ((unsigned)lo[3] << 16);
    pl.z = (unsigned)lo[4] | ((unsigned)lo[5] << 16);
    pl.w = (unsigned)lo[6] | ((unsigned)lo[7] << 16);
    *(uint4*)(Xhi + (size_t)r * DIMS + seg * 8) = ph;
    *(uint4*)(Xlo + (size_t)r * DIMS + seg * 8) = pl;
}

#define MFMA3(acc, ah, al, bh, bl)                                        \
    acc = __builtin_amdgcn_mfma_f32_16x16x32_bf16(al, bh, acc, 0, 0, 0);  \
    acc = __builtin_amdgcn_mfma_f32_16x16x32_bf16(ah, bl, acc, 0, 0, 0);  \
    acc = __builtin_amdgcn_mfma_f32_16x16x32_bf16(ah, bh, acc, 0, 0, 0);

// K2: kNN. blockIdx.y: 0 -> Y=Q (nusqQ), 1 -> Y=P (nusqP). Block = 512 thr =
// 8 waves owns 32 queries; wave w scans candidate tiles [w*64, (w+1)*64).
// acc = -sq/2; keep top-4 LARGEST acc == top-4 smallest sq.
__global__ __launch_bounds__(512, 4)
void knn_mfma(const unsigned short* __restrict__ Phi, const unsigned short* __restrict__ Plo,
              const unsigned short* __restrict__ Qhi, const unsigned short* __restrict__ Qlo,
              const float* __restrict__ normP, const float* __restrict__ normQ,
              float* __restrict__ nusqP, float* __restrict__ nusqQ) {
    __shared__ float ldsM[32 * 32 * 4];
    __shared__ float ldsM2[32 * 8 * 4];
    const unsigned short *Yhi, *Ylo; const float* nY; float* out;
    if (blockIdx.y == 0) { Yhi = Qhi; Ylo = Qlo; nY = normQ; out = nusqQ; }
    else                 { Yhi = Phi; Ylo = Plo; nY = normP; out = nusqP; }
    const int tid = threadIdx.x;
    const int w = tid >> 6, l = tid & 63, q = l & 15, quad = l >> 4;
    const int q0 = blockIdx.x * 32;

    const int rb0 = q0 + q, rb1 = q0 + 16 + q;
    bf16x8 bh0 = *(const bf16x8*)(Yhi + rb0 * DIMS + quad * 8);
    bf16x8 bl0 = *(const bf16x8*)(Ylo + rb0 * DIMS + quad * 8);
    bf16x8 bh1 = *(const bf16x8*)(Yhi + rb1 * DIMS + quad * 8);
    bf16x8 bl1 = *(const bf16x8*)(Ylo + rb1 * DIMS + quad * 8);
    const float nB0 = nY[rb0], nB1 = nY[rb1];    // already -0.5*|y|^2

    float t0[2], t1[2], t2[2], t3[2];
#pragma unroll
    for (int s = 0; s < 2; ++s) t0[s] = t1[s] = t2[s] = t3[s] = -3.4e38f;

    const unsigned short* pH = Yhi + ((size_t)(w * 64) * 16 + q) * DIMS + quad * 8;
    const unsigned short* pL = Ylo + ((size_t)(w * 64) * 16 + q) * DIMS + quad * 8;
    const float* pN = nY + (w * 64) * 16 + quad * 4;

    for (int i = 0; i < 32; ++i) {
        bf16x8 ah0 = *(const bf16x8*)(pH);
        bf16x8 al0 = *(const bf16x8*)(pL);
        float4 nA0 = *(const float4*)(pN);
        bf16x8 ah1 = *(const bf16x8*)(pH + 16 * DIMS);
        bf16x8 al1 = *(const bf16x8*)(pL + 16 * DIMS);
        float4 nA1 = *(const float4*)(pN + 16);
        pH += 32 * DIMS; pL += 32 * DIMS; pN += 32;

        f32x4 acc0 = {nA0.x + nB0, nA0.y + nB0, nA0.z + nB0, nA0.w + nB0};
        f32x4 acc1 = {nA0.x + nB1, nA0.y + nB1, nA0.z + nB1, nA0.w + nB1};
        MFMA3(acc0, ah0, al0, bh0, bl0);
        MFMA3(acc1, ah0, al0, bh1, bl1);
#pragma unroll
        for (int r = 0; r < 4; ++r) {
            top4L_insert(acc0[r], t0[0], t1[0], t2[0], t3[0]);
            top4L_insert(acc1[r], t0[1], t1[1], t2[1], t3[1]);
        }

        f32x4 acc2 = {nA1.x + nB0, nA1.y + nB0, nA1.z + nB0, nA1.w + nB0};
        f32x4 acc3 = {nA1.x + nB1, nA1.y + nB1, nA1.z + nB1, nA1.w + nB1};
        MFMA3(acc2, ah1, al1, bh0, bl0);
        MFMA3(acc3, ah1, al1, bh1, bl1);
#pragma unroll
        for (int r = 0; r < 4; ++r) {
            top4L_insert(acc2[r], t0[0], t1[0], t2[0], t3[0]);
            top4L_insert(acc3[r], t0[1], t1[1], t2[1], t3[1]);
        }
    }

#pragma unroll
    for (int s = 0; s < 2; ++s) {
        int li = ((q + s * 16) * 32 + (w * 4 + quad)) * 4;
        *(float4*)&ldsM[li] = make_float4(t0[s], t1[s], t2[s], t3[s]);
    }
    __syncthreads();
    if (tid < 256) {
        int qq = tid >> 3, c = tid & 7;
        float a0 = -3.4e38f, a1 = a0, a2 = a0, a3 = a0;
        const float* src = &ldsM[(qq * 32 + c * 4) * 4];
#pragma unroll
        for (int s = 0; s < 16; ++s) top4L_insert(src[s], a0, a1, a2, a3);
        *(float4*)&ldsM2[(qq * 8 + c) * 4] = make_float4(a0, a1, a2, a3);
    }
    __syncthreads();
    if (tid < 32) {
        float a0 = -3.4e38f, a1 = a0, a2 = a0, a3 = a0;
        const float* src = &ldsM2[tid * 32];
#pragma unroll
        for (int s = 0; s < 32; ++s) top4L_insert(src[s], a0, a1, a2, a3);
        out[q0 + tid] = fmaxf(-2.0f * a3, 1e-12f);   // nu^2 (sq domain)
    }
}

// K3: counts. blockIdx.y==0: queries=Q (thresh nusqQ -> countQ), cands=P;
// ==1: queries=P, cands=Q -> countP. acc = -sq/2; sq<=nusq <=> acc >= -nusq/2.
__global__ __launch_bounds__(512, 4)
void count_mfma(const unsigned short* __restrict__ Phi, const unsigned short* __restrict__ Plo,
                const unsigned short* __restrict__ Qhi, const unsigned short* __restrict__ Qlo,
                const float* __restrict__ normP, const float* __restrict__ normQ,
                const float* __restrict__ nusqP, const float* __restrict__ nusqQ,
                int* __restrict__ countP, int* __restrict__ countQ) {
    __shared__ int ldsC[32 * 32];
    const unsigned short *Ahi, *Alo, *Bhi, *Blo;
    const float *nCand, *nQry, *thB; int* out;
    if (blockIdx.y == 0) { Ahi = Phi; Alo = Plo; Bhi = Qhi; Blo = Qlo;
                           nCand = normP; nQry = normQ; thB = nusqQ; out = countQ; }
    else                 { Ahi = Qhi; Alo = Qlo; Bhi = Phi; Blo = Plo;
                           nCand = normQ; nQry = normP; thB = nusqP; out = countP; }
    const int tid = threadIdx.x;
    const int w = tid >> 6, l = tid & 63, q = l & 15, quad = l >> 4;
    const int q0 = blockIdx.x * 32;

    const int rb0 = q0 + q, rb1 = q0 + 16 + q;
    bf16x8 bh0 = *(const bf16x8*)(Bhi + rb0 * DIMS + quad * 8);
    bf16x8 bl0 = *(const bf16x8*)(Blo + rb0 * DIMS + quad * 8);
    bf16x8 bh1 = *(const bf16x8*)(Bhi + rb1 * DIMS + quad * 8);
    bf16x8 bl1 = *(const bf16x8*)(Blo + rb1 * DIMS + quad * 8);
    const float nB0 = nQry[rb0], nB1 = nQry[rb1];
    const float tau0 = -0.5f * thB[rb0], tau1 = -0.5f * thB[rb1];

    int cnt0 = 0, cnt1 = 0;
    const unsigned short* pH = Ahi + ((size_t)(w * 64) * 16 + q) * DIMS + quad * 8;
    const unsigned short* pL = Alo + ((size_t)(w * 64) * 16 + q) * DIMS + quad * 8;
    const float* pN = nCand + (w * 64) * 16 + quad * 4;

    for (int i = 0; i < 32; ++i) {
        bf16x8 ah0 = *(const bf16x8*)(pH);
        bf16x8 al0 = *(const bf16x8*)(pL);
        float4 nA0 = *(const float4*)(pN);
        bf16x8 ah1 = *(const bf16x8*)(pH + 16 * DIMS);
        bf16x8 al1 = *(const bf16x8*)(pL + 16 * DIMS);
        float4 nA1 = *(const float4*)(pN + 16);
        pH += 32 * DIMS; pL += 32 * DIMS; pN += 32;

        f32x4 acc0 = {nA0.x + nB0, nA0.y + nB0, nA0.z + nB0, nA0.w + nB0};
        f32x4 acc1 = {nA0.x + nB1, nA0.y + nB1, nA0.z + nB1, nA0.w + nB1};
        MFMA3(acc0, ah0, al0, bh0, bl0);
        MFMA3(acc1, ah0, al0, bh1, bl1);
#pragma unroll
        for (int r = 0; r < 4; ++r) {
            cnt0 += (acc0[r] >= tau0) ? 1 : 0;
            cnt1 += (acc1[r] >= tau1) ? 1 : 0;
        }
        f32x4 acc2 = {nA1.x + nB0, nA1.y + nB0, nA1.z + nB0, nA1.w + nB0};
        f32x4 acc3 = {nA1.x + nB1, nA1.y + nB1, nA1.z + nB1, nA1.w + nB1};
        MFMA3(acc2, ah1, al1, bh0, bl0);
        MFMA3(acc3, ah1, al1, bh1, bl1);
#pragma unroll
        for (int r = 0; r < 4; ++r) {
            cnt0 += (acc2[r] >= tau0) ? 1 : 0;
            cnt1 += (acc3[r] >= tau1) ? 1 : 0;
        }
    }
    ldsC[q * 32 + (w * 4 + quad)] = cnt0;
    ldsC[(q + 16) * 32 + (w * 4 + quad)] = cnt1;
    __syncthreads();
    if (tid < 32) {
        int s = 0;
#pragma unroll
        for (int u = 0; u < 32; ++u) s += ldsC[tid * 32 + u];
        out[q0 + tid] = s;
    }
}

// K4: scalar epilogue, exact fp32 clip/pow semantics of the reference
__global__ void final_kernel(const int* __restrict__ countP, const int* __restrict__ countQ,
                             const float* __restrict__ nusqP, const float* __restrict__ nusqQ,
                             float* __restrict__ out) {
    __shared__ int    redi[256];
    __shared__ double redd[256];
    const int tid = threadIdx.x;
    int sQ = 0, sP = 0;
    for (int j = tid; j < MPTS; j += 256) { sQ += countQ[j]; sP += countP[j]; }
    redi[tid] = sQ; __syncthreads();
    for (int o = 128; o > 0; o >>= 1) { if (tid < o) redi[tid] += redi[tid + o]; __syncthreads(); }
    int totQ = redi[0]; __syncthreads();
    redi[tid] = sP; __syncthreads();
    for (int o = 128; o > 0; o >>= 1) { if (tid < o) redi[tid] += redi[tid + o]; __syncthreads(); }
    int totP = redi[0]; __syncthreads();

    const float kq_term = 3.0f / 24576.0f;
    float kpQ = (float)totQ + 1e-20f;
    float kpP = (float)totP + 1e-20f;
    double rQ = 0.0, rP = 0.0;
    for (int j = tid; j < MPTS; j += 256) {
        {
            float nu = sqrtf(nusqQ[j]);
            float x = nu * nu; x *= x; x *= x; x *= x; x *= x;   // nu^32
            float inv = 1.0f / (x + 1e-20f);
            float p_den = ((float)countQ[j] / kpQ) * inv;
            p_den = fminf(fmaxf(p_den, 1e-20f), 1e10f);
            float q_den = kq_term * inv;
            q_den = fminf(fmaxf(q_den, 1e-20f), 1e10f);
            rQ += (double)((p_den / q_den) * kq_term);
        }
        {
            float nu = sqrtf(nusqP[j]);
            float x = nu * nu; x *= x; x *= x; x *= x; x *= x;
            float inv = 1.0f / (x + 1e-20f);
            float p_den = ((float)countP[j] / kpP) * inv;
            p_den = fminf(fmaxf(p_den, 1e-20f), 1e10f);
            float q_den = kq_term * inv;
            q_den = fminf(fmaxf(q_den, 1e-20f), 1e10f);
            rP += (double)((p_den / q_den) * kq_term);
        }
    }
    redd[tid] = rQ; __syncthreads();
    for (int o = 128; o > 0; o >>= 1) { if (tid < o) redd[tid] += redd[tid + o]; __syncthreads(); }
    double RQ = redd[0]; __syncthreads();
    redd[tid] = rP; __syncthreads();
    for (int o = 128; o > 0; o >>= 1) { if (tid < o) redd[tid] += redd[tid + o]; __syncthreads(); }
    if (tid == 0) {
        double RP = redd[0];
        float divP = fmaxf(0.0f, logf((float)RQ));
        float divQ = fmaxf(0.0f, logf((float)RP));
        out[0] = fmaxf(divP, divQ);
    }
}

extern "C" void kernel_launch(void* const* d_in, const int* in_sizes, int n_in,
                              void* d_out, int out_size, void* d_ws, size_t ws_size,
                              hipStream_t stream) {
    const float* P = (const float*)d_in[0];
    const float* Q = (const float*)d_in[1];
    float* out = (float*)d_out;

    unsigned short* Phi = (unsigned short*)d_ws;
    unsigned short* Plo = Phi + MPTS * DIMS;
    unsigned short* Qhi = Plo + MPTS * DIMS;
    unsigned short* Qlo = Qhi + MPTS * DIMS;
    float* normP = (float*)(Qlo + MPTS * DIMS);
    float* normQ = normP + MPTS;
    float* nusqP = normQ + MPTS;
    float* nusqQ = nusqP + MPTS;
    int* countP  = (int*)(nusqQ + MPTS);
    int* countQ  = countP + MPTS;

    prep_kernel<<<256, 256, 0, stream>>>(P, Q, Phi, Plo, Qhi, Qlo, normP, normQ);
    knn_mfma<<<dim3(MPTS / 32, 2), 512, 0, stream>>>(Phi, Plo, Qhi, Qlo, normP, normQ, nusqP, nusqQ);
    count_mfma<<<dim3(MPTS / 32, 2), 512, 0, stream>>>(Phi, Plo, Qhi, Qlo, normP, normQ,
                                                       nusqP, nusqQ, countP, countQ);
    final_kernel<<<1, 256, 0, stream>>>(countP, countQ, nusqP, nusqQ, out);
}

// Round 5
// 132.592 us; speedup vs baseline: 3.5917x; 1.2213x over previous
//
#include <hip/hip_runtime.h>
#include <math.h>

#define MPTS 8192
#define DIMS 32
#define SPLIT 2          // candidate-dimension split (occupancy)

typedef __bf16 bf16x8 __attribute__((ext_vector_type(8)));
typedef float  f32x4  __attribute__((ext_vector_type(4)));

// Insert v into sorted-DESCENDING top-4 (t0>=t1>=t2>=t3): 1 max + 3 med3.
__device__ __forceinline__ void top4L_insert(float v, float& t0, float& t1, float& t2, float& t3) {
    float n0 = fmaxf(t0, v);
    float n1 = __builtin_amdgcn_fmed3f(v, t0, t1);
    float n2 = __builtin_amdgcn_fmed3f(v, t1, t2);
    float n3 = __builtin_amdgcn_fmed3f(v, t2, t3);
    t0 = n0; t1 = n1; t2 = n2; t3 = n3;
}

__device__ __forceinline__ unsigned short f32_to_bf16_rne(float x) {
    unsigned u = __float_as_uint(x);
    unsigned r = u + 0x7FFFu + ((u >> 16) & 1u);
    return (unsigned short)(r >> 16);
}

// K1: bf16 conversion of P,Q + norms pre-scaled by -0.5 ( -|x|^2/2 ), zero counts.
__global__ void prep_kernel(const float* __restrict__ P, const float* __restrict__ Q,
                            unsigned short* __restrict__ Phi, unsigned short* __restrict__ Qhi,
                            float* __restrict__ normP, float* __restrict__ normQ,
                            int* __restrict__ countP, int* __restrict__ countQ) {
    int t = blockIdx.x * 256 + threadIdx.x;          // 0 .. 65535
    int mat = t >> 15;                               // 0 = P, 1 = Q
    int idx = t & 32767;
    int r = idx >> 2, seg = idx & 3;                 // 8 elements per thread
    const float* X = mat ? Q : P;
    unsigned short* Xhi = mat ? Qhi : Phi;
    float* nX = mat ? normQ : normP;
    int* cX = mat ? countQ : countP;

    const float* src = X + (size_t)r * DIMS + seg * 8;
    float4 v0 = *(const float4*)(src);
    float4 v1 = *(const float4*)(src + 4);
    float f[8] = {v0.x, v0.y, v0.z, v0.w, v1.x, v1.y, v1.z, v1.w};

    float p = 0.f;
#pragma unroll
    for (int k = 0; k < 8; ++k) p = fmaf(f[k], f[k], p);
    p += __shfl_xor(p, 1);
    p += __shfl_xor(p, 2);      // seg groups of 4 are lane-aligned
    if (seg == 0) { nX[r] = -0.5f * p; cX[r] = 0; }

    unsigned short h[8];
#pragma unroll
    for (int k = 0; k < 8; ++k) h[k] = f32_to_bf16_rne(f[k]);
    uint4 ph;
    ph.x = (unsigned)h[0] | ((unsigned)h[1] << 16);
    ph.y = (unsigned)h[2] | ((unsigned)h[3] << 16);
    ph.z = (unsigned)h[4] | ((unsigned)h[5] << 16);
    ph.w = (unsigned)h[6] | ((unsigned)h[7] << 16);
    *(uint4*)(Xhi + (size_t)r * DIMS + seg * 8) = ph;
}

// K2: kNN partials. grid (MPTS/32, 2 mats, SPLIT). Block = 512 thr = 8 waves,
// owns 32 queries; scans candidates [z*4096, (z+1)*4096), wave w gets 512.
// acc = dot - na/2 (s-domain: larger == closer; per-query shift nb is constant
// so ranking/thresholding per query is exact). Writes per-(block,query) top-4
// (desc, s-domain) to parts[mat][z][query].
__global__ __launch_bounds__(512, 4)
void knn_mfma(const unsigned short* __restrict__ Phi, const unsigned short* __restrict__ Qhi,
              const float* __restrict__ normP, const float* __restrict__ normQ,
              float4* __restrict__ parts) {
    __shared__ float ldsM[32 * 32 * 4];
    __shared__ float ldsM2[32 * 8 * 4];
    const unsigned short* Yhi; const float* nY; int mat;
    if (blockIdx.y == 0) { Yhi = Qhi; nY = normQ; mat = 0; }
    else                 { Yhi = Phi; nY = normP; mat = 1; }
    const int tid = threadIdx.x;
    const int w = tid >> 6, l = tid & 63, q = l & 15, quad = l >> 4;
    const int q0 = blockIdx.x * 32;
    const int z = blockIdx.z;

    bf16x8 bh0 = *(const bf16x8*)(Yhi + (size_t)(q0 + q) * DIMS + quad * 8);
    bf16x8 bh1 = *(const bf16x8*)(Yhi + (size_t)(q0 + 16 + q) * DIMS + quad * 8);

    float t0[2], t1[2], t2[2], t3[2];
#pragma unroll
    for (int s = 0; s < 2; ++s) t0[s] = t1[s] = t2[s] = t3[s] = -3.4e38f;

    const int c0 = z * (MPTS / SPLIT) + w * (MPTS / SPLIT / 8);
    const unsigned short* pH = Yhi + ((size_t)c0 + q) * DIMS + quad * 8;
    const float* pN = nY + c0 + quad * 4;

    for (int i = 0; i < 16; ++i) {
        bf16x8 ah0 = *(const bf16x8*)(pH);
        float4 nA0 = *(const float4*)(pN);
        bf16x8 ah1 = *(const bf16x8*)(pH + 16 * DIMS);
        float4 nA1 = *(const float4*)(pN + 16);
        pH += 32 * DIMS; pN += 32;

        f32x4 c0v = {nA0.x, nA0.y, nA0.z, nA0.w};
        f32x4 c1v = {nA1.x, nA1.y, nA1.z, nA1.w};
        f32x4 acc0 = __builtin_amdgcn_mfma_f32_16x16x32_bf16(ah0, bh0, c0v, 0, 0, 0);
        f32x4 acc1 = __builtin_amdgcn_mfma_f32_16x16x32_bf16(ah0, bh1, c0v, 0, 0, 0);
        f32x4 acc2 = __builtin_amdgcn_mfma_f32_16x16x32_bf16(ah1, bh0, c1v, 0, 0, 0);
        f32x4 acc3 = __builtin_amdgcn_mfma_f32_16x16x32_bf16(ah1, bh1, c1v, 0, 0, 0);
#pragma unroll
        for (int r = 0; r < 4; ++r) {
            top4L_insert(acc0[r], t0[0], t1[0], t2[0], t3[0]);
            top4L_insert(acc1[r], t0[1], t1[1], t2[1], t3[1]);
        }
#pragma unroll
        for (int r = 0; r < 4; ++r) {
            top4L_insert(acc2[r], t0[0], t1[0], t2[0], t3[0]);
            top4L_insert(acc3[r], t0[1], t1[1], t2[1], t3[1]);
        }
    }

    // merge 32 per-wave-quad lists per query -> block top-4
#pragma unroll
    for (int s = 0; s < 2; ++s) {
        int li = ((q + s * 16) * 32 + (w * 4 + quad)) * 4;
        *(float4*)&ldsM[li] = make_float4(t0[s], t1[s], t2[s], t3[s]);
    }
    __syncthreads();
    if (tid < 256) {
        int qq = tid >> 3, c = tid & 7;
        float a0 = -3.4e38f, a1 = a0, a2 = a0, a3 = a0;
        const float* src = &ldsM[(qq * 32 + c * 4) * 4];
#pragma unroll
        for (int s = 0; s < 16; ++s) top4L_insert(src[s], a0, a1, a2, a3);
        *(float4*)&ldsM2[(qq * 8 + c) * 4] = make_float4(a0, a1, a2, a3);
    }
    __syncthreads();
    if (tid < 32) {
        float a0 = -3.4e38f, a1 = a0, a2 = a0, a3 = a0;
        const float* src = &ldsM2[tid * 32];
#pragma unroll
        for (int s = 0; s < 32; ++s) top4L_insert(src[s], a0, a1, a2, a3);
        parts[((size_t)(mat * SPLIT + z)) * MPTS + q0 + tid] = make_float4(a0, a1, a2, a3);
    }
}

// K3: counts. grid (MPTS/32, 2 dirs, SPLIT). y==0: queries=Q, cands=P -> countQ;
// y==1: queries=P, cands=Q -> countP. Prologue merges knn parts -> nu^2 (writes
// nusq once, z==0) and s-domain threshold tau; sq<=nu2 <=> s>=tau.
__global__ __launch_bounds__(512, 4)
void count_mfma(const unsigned short* __restrict__ Phi, const unsigned short* __restrict__ Qhi,
                const float* __restrict__ normP, const float* __restrict__ normQ,
                const float4* __restrict__ parts,
                float* __restrict__ nusqP, float* __restrict__ nusqQ,
                int* __restrict__ countP, int* __restrict__ countQ) {
    __shared__ int   ldsC[32 * 32];
    __shared__ float ldsTau[32];
    const unsigned short *Ahi, *Bhi;
    const float *nCand, *nQry; float* nusqOut; int* out; int slot;
    if (blockIdx.y == 0) { Ahi = Phi; Bhi = Qhi; nCand = normP; nQry = normQ;
                           nusqOut = nusqQ; out = countQ; slot = 0; }
    else                 { Ahi = Qhi; Bhi = Phi; nCand = normQ; nQry = normP;
                           nusqOut = nusqP; out = countP; slot = 1; }
    const int tid = threadIdx.x;
    const int w = tid >> 6, l = tid & 63, q = l & 15, quad = l >> 4;
    const int q0 = blockIdx.x * 32;
    const int z = blockIdx.z;

    // prologue: merge the SPLIT partial top-4 lists for this block's queries
    if (tid < 32) {
        int qq = q0 + tid;
        float4 f0 = parts[(size_t)(slot * SPLIT + 0) * MPTS + qq];
        float a0 = f0.x, a1 = f0.y, a2 = f0.z, a3 = f0.w;       // already desc
#pragma unroll
        for (int s = 1; s < SPLIT; ++s) {
            float4 f1 = parts[(size_t)(slot * SPLIT + s) * MPTS + qq];
            top4L_insert(f1.x, a0, a1, a2, a3);
            top4L_insert(f1.y, a0, a1, a2, a3);
            top4L_insert(f1.z, a0, a1, a2, a3);
            top4L_insert(f1.w, a0, a1, a2, a3);
        }
        float nb = -2.0f * nQry[qq];                 // |q|^2
        float nu2 = fmaxf(nb - 2.0f * a3, 1e-12f);   // sq-domain nu^2, clamped
        if (z == 0) nusqOut[qq] = nu2;
        ldsTau[tid] = 0.5f * (nb - nu2);             // s-domain threshold
    }

    bf16x8 bh0 = *(const bf16x8*)(Bhi + (size_t)(q0 + q) * DIMS + quad * 8);
    bf16x8 bh1 = *(const bf16x8*)(Bhi + (size_t)(q0 + 16 + q) * DIMS + quad * 8);
    __syncthreads();
    const float tau0 = ldsTau[q], tau1 = ldsTau[q + 16];

    int cnt0 = 0, cnt1 = 0;
    const int c0 = z * (MPTS / SPLIT) + w * (MPTS / SPLIT / 8);
    const unsigned short* pH = Ahi + ((size_t)c0 + q) * DIMS + quad * 8;
    const float* pN = nCand + c0 + quad * 4;

    for (int i = 0; i < 16; ++i) {
        bf16x8 ah0 = *(const bf16x8*)(pH);
        float4 nA0 = *(const float4*)(pN);
        bf16x8 ah1 = *(const bf16x8*)(pH + 16 * DIMS);
        float4 nA1 = *(const float4*)(pN + 16);
        pH += 32 * DIMS; pN += 32;

        f32x4 c0v = {nA0.x, nA0.y, nA0.z, nA0.w};
        f32x4 c1v = {nA1.x, nA1.y, nA1.z, nA1.w};
        f32x4 acc0 = __builtin_amdgcn_mfma_f32_16x16x32_bf16(ah0, bh0, c0v, 0, 0, 0);
        f32x4 acc1 = __builtin_amdgcn_mfma_f32_16x16x32_bf16(ah0, bh1, c0v, 0, 0, 0);
        f32x4 acc2 = __builtin_amdgcn_mfma_f32_16x16x32_bf16(ah1, bh0, c1v, 0, 0, 0);
        f32x4 acc3 = __builtin_amdgcn_mfma_f32_16x16x32_bf16(ah1, bh1, c1v, 0, 0, 0);
#pragma unroll
        for (int r = 0; r < 4; ++r) {
            cnt0 += (acc0[r] >= tau0) ? 1 : 0;
            cnt1 += (acc1[r] >= tau1) ? 1 : 0;
            cnt0 += (acc2[r] >= tau0) ? 1 : 0;
            cnt1 += (acc3[r] >= tau1) ? 1 : 0;
        }
    }
    ldsC[q * 32 + (w * 4 + quad)] = cnt0;
    ldsC[(q + 16) * 32 + (w * 4 + quad)] = cnt1;
    __syncthreads();
    if (tid < 32) {
        int s = 0;
#pragma unroll
        for (int u = 0; u < 32; ++u) s += ldsC[tid * 32 + u];
        if (s) atomicAdd(&out[q0 + tid], s);
    }
}

// K4: scalar epilogue, exact fp32 clip/pow semantics of the reference
__global__ void final_kernel(const int* __restrict__ countP, const int* __restrict__ countQ,
                             const float* __restrict__ nusqP, const float* __restrict__ nusqQ,
                             float* __restrict__ out) {
    __shared__ int    redi[256];
    __shared__ double redd[256];
    const int tid = threadIdx.x;
    int sQ = 0, sP = 0;
    for (int j = tid; j < MPTS; j += 256) { sQ += countQ[j]; sP += countP[j]; }
    redi[tid] = sQ; __syncthreads();
    for (int o = 128; o > 0; o >>= 1) { if (tid < o) redi[tid] += redi[tid + o]; __syncthreads(); }
    int totQ = redi[0]; __syncthreads();
    redi[tid] = sP; __syncthreads();
    for (int o = 128; o > 0; o >>= 1) { if (tid < o) redi[tid] += redi[tid + o]; __syncthreads(); }
    int totP = redi[0]; __syncthreads();

    const float kq_term = 3.0f / 24576.0f;
    float kpQ = (float)totQ + 1e-20f;
    float kpP = (float)totP + 1e-20f;
    double rQ = 0.0, rP = 0.0;
    for (int j = tid; j < MPTS; j += 256) {
        {
            float nu = sqrtf(nusqQ[j]);
            float x = nu * nu; x *= x; x *= x; x *= x; x *= x;   // nu^32
            float inv = 1.0f / (x + 1e-20f);
            float p_den = ((float)countQ[j] / kpQ) * inv;
            p_den = fminf(fmaxf(p_den, 1e-20f), 1e10f);
            float q_den = kq_term * inv;
            q_den = fminf(fmaxf(q_den, 1e-20f), 1e10f);
            rQ += (double)((p_den / q_den) * kq_term);
        }
        {
            float nu = sqrtf(nusqP[j]);
            float x = nu * nu; x *= x; x *= x; x *= x; x *= x;
            float inv = 1.0f / (x + 1e-20f);
            float p_den = ((float)countP[j] / kpP) * inv;
            p_den = fminf(fmaxf(p_den, 1e-20f), 1e10f);
            float q_den = kq_term * inv;
            q_den = fminf(fmaxf(q_den, 1e-20f), 1e10f);
            rP += (double)((p_den / q_den) * kq_term);
        }
    }
    redd[tid] = rQ; __syncthreads();
    for (int o = 128; o > 0; o >>= 1) { if (tid < o) redd[tid] += redd[tid + o]; __syncthreads(); }
    double RQ = redd[0]; __syncthreads();
    redd[tid] = rP; __syncthreads();
    for (int o = 128; o > 0; o >>= 1) { if (tid < o) redd[tid] += redd[tid + o]; __syncthreads(); }
    if (tid == 0) {
        double RP = redd[0];
        float divP = fmaxf(0.0f, logf((float)RQ));
        float divQ = fmaxf(0.0f, logf((float)RP));
        out[0] = fmaxf(divP, divQ);
    }
}

extern "C" void kernel_launch(void* const* d_in, const int* in_sizes, int n_in,
                              void* d_out, int out_size, void* d_ws, size_t ws_size,
                              hipStream_t stream) {
    const float* P = (const float*)d_in[0];
    const float* Q = (const float*)d_in[1];
    float* out = (float*)d_out;

    unsigned short* Phi = (unsigned short*)d_ws;
    unsigned short* Qhi = Phi + MPTS * DIMS;
    float* normP = (float*)(Qhi + MPTS * DIMS);
    float* normQ = normP + MPTS;
    float4* parts = (float4*)(normQ + MPTS);             // 2 mats x SPLIT x MPTS
    float* nusqP = (float*)(parts + 2 * SPLIT * MPTS);
    float* nusqQ = nusqP + MPTS;
    int* countP  = (int*)(nusqQ + MPTS);
    int* countQ  = countP + MPTS;

    prep_kernel<<<256, 256, 0, stream>>>(P, Q, Phi, Qhi, normP, normQ, countP, countQ);
    knn_mfma<<<dim3(MPTS / 32, 2, SPLIT), 512, 0, stream>>>(Phi, Qhi, normP, normQ, parts);
    count_mfma<<<dim3(MPTS / 32, 2, SPLIT), 512, 0, stream>>>(Phi, Qhi, normP, normQ, parts,
                                                              nusqP, nusqQ, countP, countQ);
    final_kernel<<<1, 256, 0, stream>>>(countP, countQ, nusqP, nusqQ, out);
}